// Round 8
// baseline (125.522 us; speedup 1.0000x reference)
//
#include <hip/hip_runtime.h>
#include <stdint.h>

// DETR post-process: per batch n of 256, top-300 of sigmoid(logits[n]) (80000
// elems), output [label, score, scaled box] per selected query.
//
// Ordering: jax top_k = score desc, tie -> lowest index. sigmoid is strictly
// monotonic, so we rank on 64-bit key (ord(logit)<<32 | ~index): descending
// key order == (score desc, index asc) exactly.
//
// R12 = R11 with the nontemporal loads through a clang ext_vector_type
// (HIP_vector_type<float,4>* is rejected by __builtin_nontemporal_load).
//   TIME BUDGET (R8-calibrated): fills 2x49.5=99 us (harness, fixed);
//   dispatch gaps ~0.4 us each; rank ~1.5-2 us; scan was ~23.5 us = 3.5 TB/s
//   across R6/R9/R10 regardless of occupancy -> scan BW is the only lever.
//   K1 (scan): 8 blocks/batch x 256 threads. SOFTWARE-PIPELINED BATCHED
//     LOADS: 4+4+2 named float4 registers issued before any consumption
//     (R8 scan showed VGPR_Count=8 -> compiler kept ONE load in flight;
//     branchy consume forced vmcnt(0) per iteration), and
//     __builtin_nontemporal_load (read-once data: don't allocate L2/L3).
//     Compaction unchanged: LDS counter + direct store to the block's
//     EXCLUSIVE 256-slot slice; TRUE count -> cnt8 slot (no zero kernel).
//   K2 (rank): one 1024-thread block per batch. Fast path iff total in
//     [TOPK, CAP] AND every slice count <= 256: slot validity is the pure
//     predicate (t&255) < c8[t>>8]. Monotone 512-bin histogram rank
//     (single-wave shfl suffix scan), scatter, exact within-bin tie count,
//     emit. Otherwise: full radix-select fallback re-reading logits
//     (arbitrary-data correct, never taken for the bench distribution).
//   If ws_size too small: monolithic R6 kernel fallback.
//
// Hard-learned rules: NO per-thread arrays with runtime indexing (R2/R3:
// scratch spill) -> batched loads use NAMED variables. No per-candidate
// global atomics (R8: 161 us). Dispatch count is nearly free (R8 arith).

#define TOPK 300
#define NCLS 80
#define NQ 1000
#define QK (NQ * NCLS)   // 80000
#define NB 2048          // fallback radix bins
#define CAP 2048
#define THREADS 1024
#define LAST_VALID 544   // j=19: 4*t + 4096*19 < 80000  <=>  t < 544
#define T0F 2.4f         // fixed fast-path threshold (z-score)
#define RNB 512          // rank bins
#define RSH 14           // rank-bin shift: bin = (ord - base) >> RSH

// K1 geometry: 8 blocks per batch, 256 threads, 10000 floats (2500 float4)
// per block. float4 index coverage: A{t,+256,+512,+768} B{+1024..+1792}
// C{+2048 (all), +2304 (t<196)}. Slice = 256 slots (bench count ~82 +- 9).
#define SBLK 8
#define STHREADS 256
#define SCHUNK 10000
#define SLAST 196
#define SLICE 256

typedef unsigned long long u64;
typedef float f4v __attribute__((ext_vector_type(4)));  // clang vector: NT-ok

__device__ __forceinline__ uint32_t ordf(float f) {
  uint32_t u = __float_as_uint(f);
  return (u & 0x80000000u) ? ~u : (u | 0x80000000u);  // monotonic float->uint
}
__device__ __forceinline__ float unordf(uint32_t o) {
  uint32_t u = (o & 0x80000000u) ? (o & 0x7fffffffu) : ~o;
  return __uint_as_float(u);
}
__device__ __forceinline__ u64 mkkey(uint32_t ord, uint32_t idx) {
  return ((u64)ord << 32) | (u64)(~idx);
}

// ---------------- K1: pipelined NT streaming scan -> exclusive slice -------
__global__ __launch_bounds__(STHREADS) void scan_kernel(
    const float* __restrict__ logits, u64* __restrict__ cand,
    uint32_t* __restrict__ cnt8) {
  __shared__ uint32_t lcnt;

  const int n = blockIdx.x >> 3;        // batch
  const int rb = blockIdx.x & 7;        // chunk within batch
  const int t = threadIdx.x;
  const int coff = rb * SCHUNK;
  const f4v* base = (const f4v*)(logits + (size_t)n * QK + coff);
  u64* slice = cand + (size_t)n * CAP + (size_t)rb * SLICE;

  if (t == 0) lcnt = 0;
  __syncthreads();

#define PROC(vv, f4i)                                                        \
  do {                                                                       \
    const int gi_ = coff + 4 * (f4i);                                        \
    if ((vv)[0] >= T0F) {                                                    \
      const uint32_t p = atomicAdd(&lcnt, 1u);                               \
      if (p < SLICE) slice[p] = mkkey(ordf((vv)[0]), (uint32_t)(gi_ + 0));   \
    }                                                                        \
    if ((vv)[1] >= T0F) {                                                    \
      const uint32_t p = atomicAdd(&lcnt, 1u);                               \
      if (p < SLICE) slice[p] = mkkey(ordf((vv)[1]), (uint32_t)(gi_ + 1));   \
    }                                                                        \
    if ((vv)[2] >= T0F) {                                                    \
      const uint32_t p = atomicAdd(&lcnt, 1u);                               \
      if (p < SLICE) slice[p] = mkkey(ordf((vv)[2]), (uint32_t)(gi_ + 2));   \
    }                                                                        \
    if ((vv)[3] >= T0F) {                                                    \
      const uint32_t p = atomicAdd(&lcnt, 1u);                               \
      if (p < SLICE) slice[p] = mkkey(ordf((vv)[3]), (uint32_t)(gi_ + 3));   \
    }                                                                        \
  } while (0)

  // batch A: 4 independent NT loads issued back-to-back
  const f4v a0 = __builtin_nontemporal_load(base + t);
  const f4v a1 = __builtin_nontemporal_load(base + t + 256);
  const f4v a2 = __builtin_nontemporal_load(base + t + 512);
  const f4v a3 = __builtin_nontemporal_load(base + t + 768);
  // batch B issued before A is consumed (keeps 8 loads in flight)
  const f4v b0 = __builtin_nontemporal_load(base + t + 1024);
  const f4v b1 = __builtin_nontemporal_load(base + t + 1280);
  const f4v b2 = __builtin_nontemporal_load(base + t + 1536);
  const f4v b3 = __builtin_nontemporal_load(base + t + 1792);

  PROC(a0, t);
  PROC(a1, t + 256);
  PROC(a2, t + 512);
  PROC(a3, t + 768);

  // batch C issued before B is consumed
  const f4v c0 = __builtin_nontemporal_load(base + t + 2048);
  f4v c1 = (f4v){0.f, 0.f, 0.f, 0.f};
  if (t < SLAST) c1 = __builtin_nontemporal_load(base + t + 2304);

  PROC(b0, t + 1024);
  PROC(b1, t + 1280);
  PROC(b2, t + 1536);
  PROC(b3, t + 1792);

  PROC(c0, t + 2048);
  if (t < SLAST) PROC(c1, t + 2304);
#undef PROC

  __syncthreads();
  if (t == 0) cnt8[n * 8 + rb] = lcnt;  // TRUE count (may exceed SLICE)
}

// ---------------- shared rank+emit helper ----------------------------------
__device__ __forceinline__ void rank_emit(
    const u64 key, const uint32_t bin, const uint32_t* rcur,
    const uint32_t* rh, const u64* buf2, const float* boxes, float* out,
    const int n, const float s0, const float s1) {
  const uint32_t end = rcur[bin];          // start[bin] + count[bin]
  const uint32_t beg = end - rh[bin];
  uint32_t rank = beg;                     // #keys in strictly-higher bins
  for (uint32_t q = beg; q < end; ++q) rank += (uint32_t)(buf2[q] > key);
  if (rank < TOPK) {
    const uint32_t u = (uint32_t)(key >> 32);
    const uint32_t idx = ~(uint32_t)(key & 0xffffffffu);
    const float lgv = unordf(u);
    const float score = 1.0f / (1.0f + expf(-lgv));
    const uint32_t q = idx / NCLS;
    const uint32_t lab = idx - q * NCLS;
    const float4 b4 = *(const float4*)(boxes + ((size_t)n * NQ + q) * 4);
    float* op = out + ((size_t)n * TOPK + rank) * 6;  // 8-byte aligned
    float2* op2 = (float2*)op;
    op2[0] = make_float2((float)lab, score);
    op2[1] = make_float2((b4.x - 0.5f * b4.z) * s1, (b4.y - 0.5f * b4.w) * s0);
    op2[2] = make_float2(b4.z * s1, b4.w * s0);
  }
}

// ---------------- K2: rank + emit (fallback: radix re-reading logits) ------
__global__ __launch_bounds__(THREADS) void rank_kernel(
    const float* __restrict__ logits, const float* __restrict__ boxes,
    const int* __restrict__ osz, float* __restrict__ out,
    const u64* __restrict__ cand, const uint32_t* __restrict__ cnt8) {
  __shared__ u64 buf[CAP];       // 16 KB: fallback compaction buffer
  __shared__ u64 smem64[4096];   // 32 KB: fallback hist4 | {buf2, rh, rcur}
  __shared__ uint32_t histf[NB]; // 8 KB: fallback prefix only
  __shared__ uint32_t sh_sel[3];
  __shared__ uint32_t sh_cnt;
  __shared__ uint32_t sh_c8[8];  // per-slice counts

  uint32_t* const hist4 = (uint32_t*)smem64;        // 8192 u32 (fallback)
  u64* const buf2 = smem64;                         // 2048 u64 (rank scatter)
  uint32_t* const rh = (uint32_t*)(smem64 + 2048);  // 512 u32 (bin counts)
  uint32_t* const rcur = (uint32_t*)(smem64 + 2304);// 512 u32 (start/cursor)

  const int n = blockIdx.x;
  const int t = threadIdx.x;
  const float* lg = logits + (size_t)n * QK;

  if (t < RNB) rh[t] = 0;
  if (t < 8) sh_c8[t] = cnt8[n * 8 + t];
  __syncthreads();

  const uint32_t c0 = sh_c8[0], c1 = sh_c8[1], c2 = sh_c8[2], c3 = sh_c8[3];
  const uint32_t c4 = sh_c8[4], c5 = sh_c8[5], c6 = sh_c8[6], c7 = sh_c8[7];
  const uint32_t tot = c0 + c1 + c2 + c3 + c4 + c5 + c6 + c7;
  const uint32_t cmax =
      max(max(max(c0, c1), max(c2, c3)), max(max(c4, c5), max(c6, c7)));
  const bool fast_ok =
      (tot >= TOPK && tot <= CAP && cmax <= SLICE);  // block-uniform

  uint32_t baseord = ordf(T0F);
  u64 k0 = 0, k1 = 0;
  bool valid0 = false, valid1 = false;

  if (fast_ok) {
    // slot t -> slice t>>8, offset t&255; valid iff offset < slice count.
    // rank ignores candidate order, so validity predicate replaces gather.
    valid0 = (uint32_t)(t & 255) < sh_c8[t >> 8];
    valid1 = (uint32_t)(t & 255) < sh_c8[(t >> 8) + 4];
    const u64* cnd = cand + (size_t)n * CAP;
    if (valid0) k0 = cnd[t];
    if (valid1) k1 = cnd[t + THREADS];
  } else {
    // ---- fallback: full radix select on ord(logit), then recompact to LDS.
    // Correct for arbitrary inputs; never taken for the bench distribution.
    uint32_t T = 0, S_above = 0, Krem = TOPK;
    int prev_shift = 32;
    const uint32_t sub = (uint32_t)(t & 3);
    const int shifts[3] = {21, 10, 0};
    const int nbns[3] = {2048, 2048, 1024};

    for (int lvl = 0; lvl < 3; ++lvl) {
      const int sh = shifts[lvl];
      const uint32_t nb = (uint32_t)nbns[lvl];

      for (int b = t; b < NB * 4; b += THREADS) hist4[b] = 0;
      __syncthreads();
      for (int j = 0; j < 20; ++j) {
        if (j == 19 && t >= LAST_VALID) break;
        const int i = 4 * t + 4096 * j;
        const float4 v = *(const float4*)(lg + i);
        const float vs[4] = {v.x, v.y, v.z, v.w};
        for (int c = 0; c < 4; ++c) {
          const uint32_t u = ordf(vs[c]);
          if (lvl == 0 || (u >> prev_shift) == (T >> prev_shift))
            atomicAdd(&hist4[(((u >> sh) & (nb - 1)) << 2) | sub], 1u);
        }
      }
      __syncthreads();

      for (uint32_t b = t; b < nb; b += (uint32_t)THREADS) {
        const uint32_t i4 = b << 2;
        histf[b] = hist4[i4] + hist4[i4 + 1] + hist4[i4 + 2] + hist4[i4 + 3];
      }
      __syncthreads();

      for (uint32_t off = 1; off < nb; off <<= 1) {
        uint32_t a0 = histf[t] + ((t + off < nb) ? histf[t + off] : 0u);
        uint32_t a1 = 0;
        if (nb > (uint32_t)THREADS) {
          const uint32_t i1 = (uint32_t)t + THREADS;
          a1 = histf[i1] + ((i1 + off < nb) ? histf[i1 + off] : 0u);
        }
        __syncthreads();
        histf[t] = a0;
        if (nb > (uint32_t)THREADS) histf[(uint32_t)t + THREADS] = a1;
        __syncthreads();
      }

      for (uint32_t b = t; b < nb; b += (uint32_t)THREADS) {
        const uint32_t s = histf[b];
        const uint32_t sn = (b + 1 < nb) ? histf[b + 1] : 0u;
        if (s >= Krem && sn < Krem) {
          sh_sel[0] = b;
          sh_sel[1] = sn;
          sh_sel[2] = s;
        }
      }
      __syncthreads();
      const uint32_t bsel = sh_sel[0], above = sh_sel[1], candL = sh_sel[2];
      __syncthreads();

      T |= bsel << sh;
      if (S_above + candL <= CAP || lvl == 2) break;
      S_above += above;
      Krem -= above;
      prev_shift = sh;
    }

    // recompact with the radix-derived ordered threshold; re-zero rank bins
    if (t == 0) sh_cnt = 0;
    __syncthreads();
    if (t < RNB) rh[t] = 0;
    for (int j = 0; j < 20; ++j) {
      if (j == 19 && t >= LAST_VALID) break;
      const int i = 4 * t + 4096 * j;
      const float4 v = *(const float4*)(lg + i);
      const float vs[4] = {v.x, v.y, v.z, v.w};
      for (int c = 0; c < 4; ++c) {
        const uint32_t u = ordf(vs[c]);
        if (u >= T) {
          const uint32_t p = atomicAdd(&sh_cnt, 1u);
          if (p < CAP) buf[p] = mkkey(u, (uint32_t)(i + c));
        }
      }
    }
    __syncthreads();
    const uint32_t cnt = sh_cnt < CAP ? sh_cnt : CAP;
    baseord = T;  // all compacted keys have ord >= T
    valid0 = (uint32_t)t < cnt;
    valid1 = (uint32_t)(t + THREADS) < cnt;
    if (valid0) k0 = buf[t];
    if (valid1) k1 = buf[t + THREADS];
  }

  // ---- rank via monotone 512-bin histogram on (ord - baseord) >> RSH.
  // bin(a) > bin(b)  =>  a > b  (strict), so
  // rank(key) = (#keys in higher bins) + (#same-bin keys > key)  -- exact.
  uint32_t b0 = 0, b1 = 0;
  if (valid0) {
    b0 = ((uint32_t)(k0 >> 32) - baseord) >> RSH;
    if (b0 > RNB - 1u) b0 = RNB - 1u;
    atomicAdd(&rh[b0], 1u);
  }
  if (valid1) {
    b1 = ((uint32_t)(k1 >> 32) - baseord) >> RSH;
    if (b1 > RNB - 1u) b1 = RNB - 1u;
    atomicAdd(&rh[b1], 1u);
  }
  __syncthreads();

  // ---- single-wave suffix scan: rcur[b] = sum_{b' > b} rh[b']  (start[b])
  if (t < 64) {
    const uint4 a = *(const uint4*)&rh[8 * t];
    const uint4 b = *(const uint4*)&rh[8 * t + 4];
    const uint32_t d0 = a.x, d1 = a.y, d2 = a.z, d3 = a.w;
    const uint32_t d4 = b.x, d5 = b.y, d6 = b.z, d7 = b.w;
    const uint32_t mysum = d0 + d1 + d2 + d3 + d4 + d5 + d6 + d7;
    uint32_t s = mysum;  // inclusive suffix over lanes
    for (int d = 1; d < 64; d <<= 1) {
      const uint32_t o = __shfl_down(s, d);
      if (t + d < 64) s += o;
    }
    uint32_t acc = s - mysum;  // sum over lanes > t
    rcur[8 * t + 7] = acc; acc += d7;
    rcur[8 * t + 6] = acc; acc += d6;
    rcur[8 * t + 5] = acc; acc += d5;
    rcur[8 * t + 4] = acc; acc += d4;
    rcur[8 * t + 3] = acc; acc += d3;
    rcur[8 * t + 2] = acc; acc += d2;
    rcur[8 * t + 1] = acc; acc += d1;
    rcur[8 * t + 0] = acc;
  }
  __syncthreads();

  // ---- scatter candidates into bin-ordered slots of buf2
  if (valid0) {
    const uint32_t s = atomicAdd(&rcur[b0], 1u);
    buf2[s] = k0;
  }
  if (valid1) {
    const uint32_t s = atomicAdd(&rcur[b1], 1u);
    buf2[s] = k1;
  }
  __syncthreads();
  // now rcur[b] = start[b] + rh[b] = segment end for bin b

  const float s0 = (float)osz[0];
  const float s1 = (float)osz[1];

  if (valid0) rank_emit(k0, b0, rcur, rh, buf2, boxes, out, n, s0, s1);
  if (valid1) rank_emit(k1, b1, rcur, rh, buf2, boxes, out, n, s0, s1);
}

// ---------------- monolithic R6 kernel: used only if ws too small ----------
__global__ __launch_bounds__(THREADS) void detr_post_mono(
    const float* __restrict__ logits, const float* __restrict__ boxes,
    const int* __restrict__ osz, float* __restrict__ out) {
  __shared__ u64 buf[CAP];
  __shared__ u64 smem64[4096];
  __shared__ uint32_t histf[NB];
  __shared__ uint32_t sh_sel[3];
  __shared__ uint32_t sh_cnt;

  uint32_t* const hist4 = (uint32_t*)smem64;
  u64* const buf2 = smem64;
  uint32_t* const rh = (uint32_t*)(smem64 + 2048);
  uint32_t* const rcur = (uint32_t*)(smem64 + 2304);

  const int n = blockIdx.x;
  const int t = threadIdx.x;
  const float* lg = logits + (size_t)n * QK;

  if (t == 0) sh_cnt = 0;
  if (t < RNB) rh[t] = 0;
  __syncthreads();

#pragma unroll 5
  for (int j = 0; j < 19; ++j) {
    const int i = 4 * t + 4096 * j;
    const float4 v = *(const float4*)(lg + i);
    if (v.x >= T0F) {
      const uint32_t p = atomicAdd(&sh_cnt, 1u);
      if (p < CAP) buf[p] = mkkey(ordf(v.x), (uint32_t)(i + 0));
    }
    if (v.y >= T0F) {
      const uint32_t p = atomicAdd(&sh_cnt, 1u);
      if (p < CAP) buf[p] = mkkey(ordf(v.y), (uint32_t)(i + 1));
    }
    if (v.z >= T0F) {
      const uint32_t p = atomicAdd(&sh_cnt, 1u);
      if (p < CAP) buf[p] = mkkey(ordf(v.z), (uint32_t)(i + 2));
    }
    if (v.w >= T0F) {
      const uint32_t p = atomicAdd(&sh_cnt, 1u);
      if (p < CAP) buf[p] = mkkey(ordf(v.w), (uint32_t)(i + 3));
    }
  }
  if (t < LAST_VALID) {
    const int i = 4 * t + 4096 * 19;
    const float4 v = *(const float4*)(lg + i);
    if (v.x >= T0F) {
      const uint32_t p = atomicAdd(&sh_cnt, 1u);
      if (p < CAP) buf[p] = mkkey(ordf(v.x), (uint32_t)(i + 0));
    }
    if (v.y >= T0F) {
      const uint32_t p = atomicAdd(&sh_cnt, 1u);
      if (p < CAP) buf[p] = mkkey(ordf(v.y), (uint32_t)(i + 1));
    }
    if (v.z >= T0F) {
      const uint32_t p = atomicAdd(&sh_cnt, 1u);
      if (p < CAP) buf[p] = mkkey(ordf(v.z), (uint32_t)(i + 2));
    }
    if (v.w >= T0F) {
      const uint32_t p = atomicAdd(&sh_cnt, 1u);
      if (p < CAP) buf[p] = mkkey(ordf(v.w), (uint32_t)(i + 3));
    }
  }
  __syncthreads();

  uint32_t cnt = sh_cnt;
  const bool fast_ok = (cnt >= TOPK && cnt <= CAP);
  uint32_t baseord = ordf(T0F);

  if (!fast_ok) {
    uint32_t T = 0, S_above = 0, Krem = TOPK;
    int prev_shift = 32;
    const uint32_t sub = (uint32_t)(t & 3);
    const int shifts[3] = {21, 10, 0};
    const int nbns[3] = {2048, 2048, 1024};

    for (int lvl = 0; lvl < 3; ++lvl) {
      const int sh = shifts[lvl];
      const uint32_t nb = (uint32_t)nbns[lvl];

      for (int b = t; b < NB * 4; b += THREADS) hist4[b] = 0;
      __syncthreads();
      for (int j = 0; j < 20; ++j) {
        if (j == 19 && t >= LAST_VALID) break;
        const int i = 4 * t + 4096 * j;
        const float4 v = *(const float4*)(lg + i);
        const float vs[4] = {v.x, v.y, v.z, v.w};
        for (int c = 0; c < 4; ++c) {
          const uint32_t u = ordf(vs[c]);
          if (lvl == 0 || (u >> prev_shift) == (T >> prev_shift))
            atomicAdd(&hist4[(((u >> sh) & (nb - 1)) << 2) | sub], 1u);
        }
      }
      __syncthreads();

      for (uint32_t b = t; b < nb; b += (uint32_t)THREADS) {
        const uint32_t i4 = b << 2;
        histf[b] = hist4[i4] + hist4[i4 + 1] + hist4[i4 + 2] + hist4[i4 + 3];
      }
      __syncthreads();

      for (uint32_t off = 1; off < nb; off <<= 1) {
        uint32_t a0 = histf[t] + ((t + off < nb) ? histf[t + off] : 0u);
        uint32_t a1 = 0;
        if (nb > (uint32_t)THREADS) {
          const uint32_t i1 = (uint32_t)t + THREADS;
          a1 = histf[i1] + ((i1 + off < nb) ? histf[i1 + off] : 0u);
        }
        __syncthreads();
        histf[t] = a0;
        if (nb > (uint32_t)THREADS) histf[(uint32_t)t + THREADS] = a1;
        __syncthreads();
      }

      for (uint32_t b = t; b < nb; b += (uint32_t)THREADS) {
        const uint32_t s = histf[b];
        const uint32_t sn = (b + 1 < nb) ? histf[b + 1] : 0u;
        if (s >= Krem && sn < Krem) {
          sh_sel[0] = b;
          sh_sel[1] = sn;
          sh_sel[2] = s;
        }
      }
      __syncthreads();
      const uint32_t bsel = sh_sel[0], above = sh_sel[1], candL = sh_sel[2];
      __syncthreads();

      T |= bsel << sh;
      if (S_above + candL <= CAP || lvl == 2) break;
      S_above += above;
      Krem -= above;
      prev_shift = sh;
    }

    if (t == 0) sh_cnt = 0;
    __syncthreads();
    if (t < RNB) rh[t] = 0;
    for (int j = 0; j < 20; ++j) {
      if (j == 19 && t >= LAST_VALID) break;
      const int i = 4 * t + 4096 * j;
      const float4 v = *(const float4*)(lg + i);
      const float vs[4] = {v.x, v.y, v.z, v.w};
      for (int c = 0; c < 4; ++c) {
        const uint32_t u = ordf(vs[c]);
        if (u >= T) {
          const uint32_t p = atomicAdd(&sh_cnt, 1u);
          if (p < CAP) buf[p] = mkkey(u, (uint32_t)(i + c));
        }
      }
    }
    __syncthreads();
    cnt = sh_cnt < CAP ? sh_cnt : CAP;
    baseord = T;
  }

  const u64 k0 = ((uint32_t)t < cnt) ? buf[t] : 0ULL;
  const u64 k1 = ((uint32_t)(t + THREADS) < cnt) ? buf[t + THREADS] : 0ULL;
  uint32_t b0 = 0, b1 = 0;
  if ((uint32_t)t < cnt) {
    b0 = ((uint32_t)(k0 >> 32) - baseord) >> RSH;
    if (b0 > RNB - 1u) b0 = RNB - 1u;
    atomicAdd(&rh[b0], 1u);
  }
  if ((uint32_t)(t + THREADS) < cnt) {
    b1 = ((uint32_t)(k1 >> 32) - baseord) >> RSH;
    if (b1 > RNB - 1u) b1 = RNB - 1u;
    atomicAdd(&rh[b1], 1u);
  }
  __syncthreads();

  if (t < 64) {
    const uint4 a = *(const uint4*)&rh[8 * t];
    const uint4 b = *(const uint4*)&rh[8 * t + 4];
    const uint32_t d0 = a.x, d1 = a.y, d2 = a.z, d3 = a.w;
    const uint32_t d4 = b.x, d5 = b.y, d6 = b.z, d7 = b.w;
    const uint32_t mysum = d0 + d1 + d2 + d3 + d4 + d5 + d6 + d7;
    uint32_t s = mysum;
    for (int d = 1; d < 64; d <<= 1) {
      const uint32_t o = __shfl_down(s, d);
      if (t + d < 64) s += o;
    }
    uint32_t acc = s - mysum;
    rcur[8 * t + 7] = acc; acc += d7;
    rcur[8 * t + 6] = acc; acc += d6;
    rcur[8 * t + 5] = acc; acc += d5;
    rcur[8 * t + 4] = acc; acc += d4;
    rcur[8 * t + 3] = acc; acc += d3;
    rcur[8 * t + 2] = acc; acc += d2;
    rcur[8 * t + 1] = acc; acc += d1;
    rcur[8 * t + 0] = acc;
  }
  __syncthreads();

  if ((uint32_t)t < cnt) {
    const uint32_t s = atomicAdd(&rcur[b0], 1u);
    buf2[s] = k0;
  }
  if ((uint32_t)(t + THREADS) < cnt) {
    const uint32_t s = atomicAdd(&rcur[b1], 1u);
    buf2[s] = k1;
  }
  __syncthreads();

  const float s0 = (float)osz[0];
  const float s1 = (float)osz[1];

  if ((uint32_t)t < cnt)
    rank_emit(k0, b0, rcur, rh, buf2, boxes, out, n, s0, s1);
  if ((uint32_t)(t + THREADS) < cnt)
    rank_emit(k1, b1, rcur, rh, buf2, boxes, out, n, s0, s1);
}

extern "C" void kernel_launch(void* const* d_in, const int* in_sizes, int n_in,
                              void* d_out, int out_size, void* d_ws, size_t ws_size,
                              hipStream_t stream) {
  const float* logits = (const float*)d_in[0];
  const float* boxes = (const float*)d_in[1];
  const int* osz = (const int*)d_in[2];
  float* out = (float*)d_out;
  const int nbatch = in_sizes[0] / QK;  // 256

  // ws layout: [cnt8: nbatch*8 u32 (8 KB)][cand: nbatch*CAP u64 (4 MB)]
  const size_t cnt_bytes = 8192;
  const size_t need = cnt_bytes + (size_t)nbatch * CAP * sizeof(u64);
  if (d_ws != nullptr && ws_size >= need &&
      (size_t)nbatch * 8 * 4 <= cnt_bytes) {
    uint32_t* cnt8 = (uint32_t*)d_ws;
    u64* cand = (u64*)((char*)d_ws + cnt_bytes);
    scan_kernel<<<nbatch * SBLK, STHREADS, 0, stream>>>(logits, cand, cnt8);
    rank_kernel<<<nbatch, THREADS, 0, stream>>>(logits, boxes, osz, out, cand,
                                                cnt8);
  } else {
    detr_post_mono<<<nbatch, THREADS, 0, stream>>>(logits, boxes, osz, out);
  }
}